// Round 3
// baseline (300.302 us; speedup 1.0000x reference)
//
#include <hip/hip_runtime.h>

// Problem constants (fixed by setup_inputs)
#define DIM 512
#define NQ 64
#define BATCH 2048
#define MT 64            // batch rows per block in GEMM
#define APAD 520         // LDS row stride (bf16 elems); 1040 B = 65*16B, 16B-aligned

typedef __bf16  bf16x8  __attribute__((ext_vector_type(8)));
typedef float   floatx4 __attribute__((ext_vector_type(4)));

static __device__ inline unsigned short f2bf(float f) {
    unsigned int u = __float_as_uint(f);
    return (unsigned short)((u + 0x7fffu + ((u >> 16) & 1u)) >> 16);  // RNE
}
static __device__ inline float bf2f(unsigned short h) {
    return __uint_as_float((unsigned int)h << 16);
}
static __device__ inline unsigned int pack2(float a, float b) {
    return (unsigned)f2bf(a) | ((unsigned)f2bf(b) << 16);
}

__global__ void hsq_zero_kernel(float* p) { p[threadIdx.x] = 0.0f; }

// Expand q_coefs (n_mono, 64) -> W[k][e][d] (bf16, d contiguous), fused norm2.
// Read phase: lane = k so every qc load is one fully-consumed 256B row.
// Write phase: LDS transpose so 16 consecutive threads write one contiguous
// 256B chunk of a k-row (4x less HBM partial-line write amplification).
__global__ __launch_bounds__(256, 4)
void hsq_expand_kernel(const float* __restrict__ qc,
                       unsigned short* __restrict__ W,
                       float* __restrict__ norm2) {
    const int e    = blockIdx.x;          // 0..511
    const int dblk = blockIdx.y;          // 0..3
    const int wid  = threadIdx.x >> 6;
    const int k    = threadIdx.x & 63;    // lane = quadric index
    const int d0   = dblk * 128 + wid * 32;

    __shared__ unsigned short tv[64 * 136];   // [k][d_local 0..127], stride 136 (272B, 16B-aligned)
    __shared__ float part[4][64];

    float v[32];
#pragma unroll
    for (int s = 0; s < 32; ++s) {
        const int d = d0 + s;
        const int i = d < e ? d : e;
        const int j = d < e ? e : d;
        const int idx = i * DIM - ((i * (i - 1)) >> 1) + (j - i);
        v[s] = qc[(size_t)idx * NQ + k];
    }

    float nacc = 0.0f;                        // norm2: count each monomial once (d>=e)
#pragma unroll
    for (int s = 0; s < 32; ++s)
        if (d0 + s >= e) nacc += v[s] * v[s];

    // scale + pack 8 bf16 per 16B LDS write
#pragma unroll
    for (int t = 0; t < 4; ++t) {
        float sc[8];
#pragma unroll
        for (int q = 0; q < 8; ++q) {
            const int d = d0 + t * 8 + q;
            sc[q] = v[t * 8 + q] * ((d == e) ? 2.0f : 1.41421356237309515f);
        }
        uint4 w;
        w.x = pack2(sc[0], sc[1]); w.y = pack2(sc[2], sc[3]);
        w.z = pack2(sc[4], sc[5]); w.w = pack2(sc[6], sc[7]);
        *(uint4*)&tv[k * 136 + wid * 32 + t * 8] = w;
    }
    part[wid][k] = nacc;
    __syncthreads();

    // write phase: 4 rounds; thread t -> (k = r*16 + t/16, d_local = (t&15)*8)
#pragma unroll
    for (int r = 0; r < 4; ++r) {
        const int kk = r * 16 + (threadIdx.x >> 4);
        const int u  = threadIdx.x & 15;
        const uint4 w = *(const uint4*)&tv[kk * 136 + u * 8];
        *(uint4*)(W + ((size_t)(kk * DIM + e)) * DIM + dblk * 128 + u * 8) = w;
    }
    if (threadIdx.x < 64) {
        const float s = part[0][k] + part[1][k] + part[2][k] + part[3][k];
        atomicAdd(&norm2[k], s);
    }
}

// Main fused kernel: per block = (64 batch rows, one quadric k), flat grid
// with XCD swizzle so each XCD's concurrent blocks share ~2 W_k (1 MB in L2).
__global__ __launch_bounds__(256, 2)
void hsq_gemm_kernel(const float* __restrict__ points,
                     const unsigned short* __restrict__ W,
                     const float* __restrict__ l_coefs,
                     const float* __restrict__ free_coefs,
                     const float* __restrict__ norm2,
                     float* __restrict__ out) {
    const int L   = blockIdx.x;          // 0..2047
    const int xcd = L & 7;
    const int sl  = L >> 3;              // 0..255 per XCD
    const int k   = (xcd << 3) | (sl >> 5);   // XCD owns 8 consecutive k's
    const int mb  = sl & 31;

    const int tid  = threadIdx.x;
    const int wid  = tid >> 6;           // wave covers e in [wid*128, wid*128+128)
    const int lane = tid & 63;
    const int c    = lane & 15;          // MFMA col index
    const int quad = lane >> 4;          // MFMA k-block / D row-block

    __shared__ unsigned short As[MT * APAD];   // bf16 P tile
    __shared__ float red[4][MT][2];

    // ---- Stage A: fp32 -> bf16, 16B vectorized LDS writes (conflict-free) ----
    {
        const float* src = points + (size_t)mb * MT * DIM;
#pragma unroll
        for (int it = 0; it < 16; ++it) {
            const int lin8 = it * 256 + tid;   // 64 rows x 64 groups of 8 floats
            const int r  = lin8 >> 6;
            const int c8 = lin8 & 63;
            const float4 v1 = *(const float4*)(src + (size_t)r * DIM + c8 * 8);
            const float4 v2 = *(const float4*)(src + (size_t)r * DIM + c8 * 8 + 4);
            uint4 w;
            w.x = pack2(v1.x, v1.y); w.y = pack2(v1.z, v1.w);
            w.z = pack2(v2.x, v2.y); w.w = pack2(v2.z, v2.w);
            *(uint4*)&As[r * APAD + c8 * 8] = w;
        }
    }
    __syncthreads();

    floatx4 acc[4][8];
#pragma unroll
    for (int mt = 0; mt < 4; ++mt)
#pragma unroll
        for (int nt = 0; nt < 8; ++nt)
            acc[mt][nt] = (floatx4){0.f, 0.f, 0.f, 0.f};

    // per-lane B base: row (wid*128 + nt*16 + c), k-offset quad*8
    const unsigned short* Wb = W + (size_t)k * DIM * DIM
                                 + (size_t)(wid * 128 + c) * DIM + quad * 8;

    bf16x8 b0[8], b1[8], af[4];

#define LOADB(dst, ksI) _Pragma("unroll") \
    for (int nt = 0; nt < 8; ++nt) dst[nt] = *(const bf16x8*)(Wb + nt * 8192 + (ksI) * 32);
#define LOADA(ksI) _Pragma("unroll") \
    for (int mt = 0; mt < 4; ++mt) af[mt] = *(const bf16x8*)&As[(mt * 16 + c) * APAD + (ksI) * 32 + quad * 8];
#define DOMFMA(bb) _Pragma("unroll") \
    for (int mt = 0; mt < 4; ++mt) _Pragma("unroll") \
        for (int nt = 0; nt < 8; ++nt) \
            acc[mt][nt] = __builtin_amdgcn_mfma_f32_16x16x32_bf16(af[mt], bb[nt], acc[mt][nt], 0, 0, 0);

    // Register ping-pong: B for step n+1 loads while MFMAs of step n run.
    LOADB(b0, 0)
    for (int h = 0; h < 7; ++h) {
        LOADB(b1, 2 * h + 1)
        LOADA(2 * h)
        DOMFMA(b0)
        LOADB(b0, 2 * h + 2)
        LOADA(2 * h + 1)
        DOMFMA(b1)
    }
    LOADB(b1, 15)
    LOADA(14)
    DOMFMA(b0)
    LOADA(15)
    DOMFMA(b1)

#undef LOADB
#undef LOADA
#undef DOMFMA

    // ---- Epilogue: pv = sum_e p*(0.5g + l), pg = sum_e (g+l)^2; p from LDS ----
    float lv[8];
#pragma unroll
    for (int nt = 0; nt < 8; ++nt)
        lv[nt] = l_coefs[(wid * 128 + nt * 16 + c) * NQ + k];

#pragma unroll
    for (int mt = 0; mt < 4; ++mt) {
        float pv[4] = {0.f, 0.f, 0.f, 0.f};
        float pg[4] = {0.f, 0.f, 0.f, 0.f};
#pragma unroll
        for (int nt = 0; nt < 8; ++nt) {
            const int e  = wid * 128 + nt * 16 + c;
            const float l = lv[nt];
            const int rl = mt * 16 + quad * 4;
#pragma unroll
            for (int r = 0; r < 4; ++r) {
                const float p = bf2f(As[(rl + r) * APAD + e]);
                const float g = acc[mt][nt][r];
                pv[r] += p * (0.5f * g + l);
                const float qg = g + l;
                pg[r] += qg * qg;
            }
        }
#pragma unroll
        for (int r = 0; r < 4; ++r) {
#pragma unroll
            for (int off = 1; off < 16; off <<= 1) {
                pv[r] += __shfl_xor(pv[r], off);
                pg[r] += __shfl_xor(pg[r], off);
            }
            if (c == 0) {
                const int row = mt * 16 + quad * 4 + r;
                red[wid][row][0] = pv[r];
                red[wid][row][1] = pg[r];
            }
        }
    }
    __syncthreads();

    if (tid < MT) {
        const int row = tid;
        float v = 0.f, g = 0.f;
#pragma unroll
        for (int w = 0; w < 4; ++w) { v += red[w][row][0]; g += red[w][row][1]; }
        const float vals = fabsf(v + free_coefs[k]);
        const float nrm  = sqrtf(norm2[k]);
        const float sc   = (sqrtf(0.25f * g + vals * nrm) - 0.5f * sqrtf(g)) / nrm;
        out[(size_t)(mb * MT + row) * NQ + k] = sc;
    }
}

extern "C" void kernel_launch(void* const* d_in, const int* in_sizes, int n_in,
                              void* d_out, int out_size, void* d_ws, size_t ws_size,
                              hipStream_t stream) {
    const float* points     = (const float*)d_in[0];  // (2048, 512)
    const float* q_coefs    = (const float*)d_in[1];  // (131328, 64)
    const float* l_coefs    = (const float*)d_in[2];  // (512, 64)
    const float* free_coefs = (const float*)d_in[3];  // (1, 64)
    float* out = (float*)d_out;                       // (2048, 64)

    unsigned short* W = (unsigned short*)d_ws;        // 64*512*512 bf16 = 32 MiB
    float* norm2 = (float*)((char*)d_ws + (size_t)NQ * DIM * DIM * sizeof(unsigned short));

    hsq_zero_kernel<<<1, 64, 0, stream>>>(norm2);
    hsq_expand_kernel<<<dim3(DIM, 4), 256, 0, stream>>>(q_coefs, W, norm2);
    hsq_gemm_kernel<<<dim3(BATCH / MT * NQ), 256, 0, stream>>>(points, W, l_coefs, free_coefs, norm2, out);
}